// Round 5
// baseline (293.630 us; speedup 1.0000x reference)
//
#include <hip/hip_runtime.h>

#define BATCH 256
#define DD 15
#define HH 63
#define WW 126
#define KK 5
#define OD 3
#define OH 13
#define OWI 26
#define SPAT (DD*HH*WW)          // 119070
#define HWSZ (HH*WW)             // 7938
#define ROWS (KK*KK)             // 25
#define WPAD (OWI*KK)            // 130 (padded W extent)
#define NBLK (OD*OH*OWI)         // 1014
#define IJN  (OD*OH)             // 39

// ---------------------------------------------------------------------------
// Kernel 1: per-(batch, i, j) slab — block conv + relu + per-batch mass sums.
// stride==kernel==5 => each input voxel feeds exactly one output block, so one
// pass over x covers the conv AND mass_in = sum(x*vol).
// mass_out = sum_blocks y * (sum land*vol over block), accumulated in-flight.
// Slab h-ranges [5j-1, 5j+3] partition the padded h-axis, so x is fetched
// from HBM exactly once across the grid.
// ---------------------------------------------------------------------------
__global__ __launch_bounds__(256)
void conv_mass_kernel(const float* __restrict__ x,
                      const float* __restrict__ land,
                      const float* __restrict__ vols,
                      const float* __restrict__ Wt,
                      const float* __restrict__ bias,
                      float* __restrict__ y_small,
                      double* __restrict__ mass_in,
                      double* __restrict__ mass_out) {
    __shared__ float lds_x[ROWS * WPAD];   // (x*land) padded slab
    __shared__ float lds_lv[ROWS * WPAD];  // land*vol (0 in padding)
    __shared__ float red_y[OWI];
    __shared__ float red_m[4];

    const int tid = threadIdx.x;
    const int bij = blockIdx.x;
    const int b  = bij / IJN;
    const int ij = bij - b * IJN;
    const int i  = ij / OH;
    const int j  = ij - i * OH;

    const float* xb = x + (size_t)b * SPAT;

    // ---- load phase: float2-vectorized (rows 8B-aligned: 126*4 = 504B) -----
    float massp = 0.f;
    const int NPAIR = ROWS * (WPAD / 2);   // 25 * 65 = 1625
    for (int t = tid; t < NPAIR; t += 256) {
        int row = t / 65;                  // p*5 + q
        int wp  = (t - row * 65) * 2;      // padded w', even
        int p = row / KK, q = row - p * KK;
        int h = j * KK + q - 1;            // PH = 1
        int w0 = wp - 2;                   // PW = 2
        float2 xl = make_float2(0.f, 0.f); // x*land
        float2 lv2 = make_float2(0.f, 0.f);// land*vol
        // valid pairs have w0 even in [0,124] (then w0+1 valid too)
        if ((unsigned)h < (unsigned)HH && (unsigned)w0 < (unsigned)WW) {
            int d = i * KK + p;
            int sidx = (d * HH + h) * WW + w0;
            float2 xv = *reinterpret_cast<const float2*>(xb + sidx);
            float2 lv = *reinterpret_cast<const float2*>(land + sidx);
            float2 vv = *reinterpret_cast<const float2*>(vols + sidx);
            xl.x  = xv.x * lv.x;  xl.y  = xv.y * lv.y;
            lv2.x = lv.x * vv.x;  lv2.y = lv.y * vv.y;
            massp += xv.x * vv.x + xv.y * vv.y;   // mass_in term (raw x * vol)
        }
        *reinterpret_cast<float2*>(&lds_x [row * WPAD + wp]) = xl;
        *reinterpret_cast<float2*>(&lds_lv[row * WPAD + wp]) = lv2;
    }

    // wave-level reduce of the mass_in partial
    #pragma unroll
    for (int s = 32; s; s >>= 1) massp += __shfl_down(massp, s, 64);
    if ((tid & 63) == 0) red_m[tid >> 6] = massp;
    __syncthreads();

    // ---- compute phase: 26 blocks x 8 lanes (tid 0..207) --------------------
    const int k    = tid >> 3;
    const int lane = tid & 7;
    if (k < OWI) {
        const float* Ws = Wt + ((size_t)ij * OWI + k) * 125;  // contiguous
        const int base_w = k * KK;
        float acc = 0.f, accl = 0.f;
        for (int m = lane; m < 125; m += 8) {
            int p   = m / 25;
            int rem = m - p * 25;
            int q   = rem / 5;
            int r   = rem - q * 5;
            int li  = (p * KK + q) * WPAD + base_w + r;
            acc  = fmaf(lds_x[li], Ws[m], acc);
            accl += lds_lv[li];
        }
        #pragma unroll
        for (int s = 4; s; s >>= 1) {
            acc  += __shfl_down(acc,  s, 8);
            accl += __shfl_down(accl, s, 8);
        }
        if (lane == 0) {
            float yv = fmaxf(acc + bias[ij * OWI + k], 0.f);
            y_small[(size_t)b * NBLK + ij * OWI + k] = yv;
            red_y[k] = yv * accl;   // contribution to mass_out
        }
    }
    __syncthreads();

    if (tid == 0) {
        float mo = 0.f;
        #pragma unroll
        for (int kk = 0; kk < OWI; ++kk) mo += red_y[kk];
        float mi = red_m[0] + red_m[1] + red_m[2] + red_m[3];
        atomicAdd(mass_out + b, (double)mo);
        atomicAdd(mass_in  + b, (double)mi);
    }
}

// ---------------------------------------------------------------------------
// Kernel 2: upsample + mask + rescale writer, one WG per (b,d) plane.
// scale = mass_in/mass_out computed in-WG (fused; no separate kernel).
// The 13x26 y-tile (pre-scaled) lives in LDS; each lane owns one w-pair so
// (w+2)/5 is hoisted out of the h-loop. ~3 VALU ops/element -> memory-bound.
// ---------------------------------------------------------------------------
__global__ __launch_bounds__(256)
void out_kernel(const float* __restrict__ y_small,
                const float* __restrict__ land,
                const double* __restrict__ mass_in,
                const double* __restrict__ mass_out,
                float* __restrict__ out) {
    __shared__ float ylds[OH * OWI];       // 338 floats
    __shared__ float s_scale;

    const int bd = blockIdx.x;             // 0..3839
    const int b  = bd / DD;
    const int d  = bd - b * DD;
    const int i  = d / KK;
    const int tid = threadIdx.x;

    if (tid == 0) s_scale = (float)(mass_in[b] / mass_out[b]);
    __syncthreads();
    // 338 > 256: MUST be a strided loop (round-4 bug: tail never initialized)
    for (int t = tid; t < OH * OWI; t += 256) {
        ylds[t] = y_small[(size_t)b * NBLK + i * (OH * OWI) + t] * s_scale;
    }
    __syncthreads();

    const int lane = tid & 63;
    const int wv   = tid >> 6;
    if (lane < 63) {
        const int w0  = lane * 2;
        const int kb0 = (w0 + 2) / KK;     // hoisted: constant per thread
        const int kb1 = (w0 + 3) / KK;
        const float* landp = land + d * HWSZ + w0;
        float*       outp  = out + (size_t)b * SPAT + d * HWSZ + w0;
        for (int h = wv; h < HH; h += 4) {
            const int jb = ((h + 1) / KK) * OWI;
            float2 l2 = *reinterpret_cast<const float2*>(landp + h * WW);
            float2 o2;
            o2.x = ylds[jb + kb0] * l2.x;
            o2.y = ylds[jb + kb1] * l2.y;
            *reinterpret_cast<float2*>(outp + h * WW) = o2;
        }
    }
}

// ---------------------------------------------------------------------------
extern "C" void kernel_launch(void* const* d_in, const int* in_sizes, int n_in,
                              void* d_out, int out_size, void* d_ws, size_t ws_size,
                              hipStream_t stream) {
    const float* x    = (const float*)d_in[0];
    const float* land = (const float*)d_in[1];
    const float* vols = (const float*)d_in[2];
    const float* Wt   = (const float*)d_in[3];
    const float* bias = (const float*)d_in[4];

    char* ws = (char*)d_ws;
    double* mass_in  = (double*)(ws);          // 256 * 8  = 2048 B
    double* mass_out = (double*)(ws + 2048);   // 256 * 8  = 2048 B
    float*  y_small  = (float*) (ws + 4096);   // 259584*4 = 1,038,336 B

    // zero the mass accumulators (ws is re-poisoned 0xAA before every launch)
    hipMemsetAsync(ws, 0, 4096, stream);

    conv_mass_kernel<<<BATCH * IJN, 256, 0, stream>>>(
        x, land, vols, Wt, bias, y_small, mass_in, mass_out);

    out_kernel<<<BATCH * DD, 256, 0, stream>>>(
        y_small, land, mass_in, mass_out, (float*)d_out);
}